// Round 9
// baseline (404.586 us; speedup 1.0000x reference)
//
#include <hip/hip_runtime.h>
#include <hip/hip_fp16.h>

// Tri-plane importance-renderer sampling.
// planes: [N=4][P=3][C=32][H=256][W=256] f32
// coords: [N][M=500000][3] f32, directions unused.
// out:    [N][M][C] f32  = mean over P of bilinear samples (zeros padding,
//                          align_corners=False).
// Plane->grid mapping (from inv(_PLANES)): p0:(cx,cy)  p1:(cx,cz)  p2:(cz,cx)
//
// R8 insight: the 4-kernel counting sort costs ~112us (~ the gather itself),
// and the gather's 2 stores/lane each touch both 64B sectors of the output
// line partially -> RMW fetches (~127MB over compulsory).
// R9: (1) ONE-pass fixed-capacity binning (atomicAdd count, direct slot
// write, tail for overflow; gather early-exits empty slots) replaces the
// sort. (2) lane owns float4 #quad and #quad+4 -> each store instruction is
// one contiguous 64B sector (loads become 24x uint2, same bytes/math).

constexpr int Cc = 32, Hh = 256, Ww = 256, Pp = 3, Nn = 4;
constexpr int HWPIX = Hh * Ww;   // 65536
constexpr int NCO   = 4096;      // 16^3 coarse cells
constexpr int CAP   = 160;       // slots per cell (mean 122, +3.5 sigma)

__device__ inline unsigned spread3(unsigned x) {
    x &= 0x3FFu;
    x = (x | (x << 16)) & 0x030000FFu;
    x = (x | (x << 8))  & 0x0300F00Fu;
    x = (x | (x << 4))  & 0x030C30C3u;
    x = (x | (x << 2))  & 0x09249249u;
    return x;
}
// 12-bit Morton key from 4 bits/axis.
__device__ inline unsigned coarse_key(float cx, float cy, float cz) {
    const int a = min(max((int)((cx + 1.0f) * 8.0f), 0), 15);
    const int b = min(max((int)((cy + 1.0f) * 8.0f), 0), 15);
    const int c = min(max((int)((cz + 1.0f) * 8.0f), 0), 15);
    return spread3((unsigned)a) | (spread3((unsigned)b) << 1) | (spread3((unsigned)c) << 2);
}

// ---------------------------------------------------------------------------
// Pass 1: transpose+convert [slice][C][HW] f32 -> [slice][HW][C] fp16.
// ---------------------------------------------------------------------------
__global__ __launch_bounds__(256) void transpose_chw_hwc_h(
    const float* __restrict__ in, __half* __restrict__ out)
{
    __shared__ float lds[Cc * 257];
    const int slice = blockIdx.y;
    const int pix0  = blockIdx.x * 256;
    const int t     = threadIdx.x;

    const float* src = in + (size_t)slice * Cc * HWPIX + pix0 + t;
    #pragma unroll
    for (int c = 0; c < Cc; ++c)
        lds[c * 257 + t] = src[(size_t)c * HWPIX];
    __syncthreads();

    uint4* dst = reinterpret_cast<uint4*>(
        out + (size_t)slice * HWPIX * Cc + (size_t)pix0 * Cc);
    #pragma unroll
    for (int k = 0; k < 4; ++k) {
        const int idx = k * 256 + t;
        const int pix = idx >> 2;
        const int c0  = (idx & 3) * 8;
        unsigned r[4];
        #pragma unroll
        for (int j = 0; j < 4; ++j) {
            const __half h0 = __float2half(lds[(c0 + 2 * j + 0) * 257 + pix]);
            const __half h1 = __float2half(lds[(c0 + 2 * j + 1) * 257 + pix]);
            r[j] = (unsigned)__half_as_ushort(h0)
                 | ((unsigned)__half_as_ushort(h1) << 16);
        }
        dst[idx] = make_uint4(r[0], r[1], r[2], r[3]);
    }
}

// ---------------------------------------------------------------------------
// One-pass binning: r = atomicAdd(count[cell]); r<CAP -> slot, else tail.
// Deterministic OUTPUT regardless of atomic order (each sample writes only
// its own output slot m).
// ---------------------------------------------------------------------------
__global__ __launch_bounds__(256) void zero_u32(unsigned* __restrict__ p, int n)
{
    const int i = blockIdx.x * 256 + threadIdx.x;
    if (i < n) p[i] = 0u;
}

__global__ __launch_bounds__(256) void bin_scatter(
    const float* __restrict__ coords, unsigned* __restrict__ count,
    unsigned* __restrict__ tailcnt, unsigned* __restrict__ idx,
    unsigned* __restrict__ tail, int M)
{
    const int m = blockIdx.x * 256 + threadIdx.x;
    const int n = blockIdx.y;
    if (m >= M) return;
    const float* cp = coords + ((size_t)n * M + m) * 3;
    const unsigned k = coarse_key(cp[0], cp[1], cp[2]);
    const unsigned r = atomicAdd(&count[n * NCO + k], 1u);
    if (r < CAP) {
        idx[((size_t)n * NCO + k) * CAP + r] = (unsigned)m;  // 4B write, L2-resident window
    } else {
        const unsigned t = atomicAdd(&tailcnt[n], 1u);
        tail[(size_t)n * M + t] = (unsigned)m;
    }
}

// ---------------------------------------------------------------------------
// Gather over the slot space (NCO*CAP binned + M tail per n).
// FOUR lanes per sample; lane owns float4 #quad and #quad+4 of the output
// record -> both stores are contiguous 64B sectors (no RMW). fp16 reads as
// 2x uint2 per corner; per-plane packed __hfma2, cross-plane f32.
// Bijective XCD-chunked swizzle keeps each XCD on a contiguous Morton range.
// ---------------------------------------------------------------------------
__global__ __launch_bounds__(256) void triplane_gather_binned(
    const __half* __restrict__ tp, const unsigned* __restrict__ count,
    const unsigned* __restrict__ tailcnt, const unsigned* __restrict__ idx,
    const unsigned* __restrict__ tail, const float* __restrict__ coords,
    float* __restrict__ out, int M, int slots, int gx, int nwg)
{
    int bid = blockIdx.x;
    {   // bijective chunked XCD swizzle (m204 form)
        const int q = nwg >> 3, r = nwg & 7;
        const int xcd = bid & 7, i = bid >> 3;
        bid = (xcd < r ? xcd * (q + 1) : r * (q + 1) + (xcd - r) * q) + i;
    }
    const int n  = bid / gx;
    const int bx = bid - n * gx;
    const int gid  = bx * 256 + threadIdx.x;
    const int s    = gid >> 2;
    const int quad = gid & 3;            // 8-channel group
    if (s >= slots) return;

    int m;
    if (s < NCO * CAP) {
        const int cell = s / CAP;                 // magic-mul division
        const int r    = s - cell * CAP;
        const unsigned cnt = count[n * NCO + cell];
        if ((unsigned)r >= cnt) return;           // r < CAP by construction
        m = (int)idx[(size_t)n * NCO * CAP + s];
    } else {
        const int t = s - NCO * CAP;
        if ((unsigned)t >= tailcnt[n]) return;
        m = (int)tail[(size_t)n * M + t];
    }

    const float* cp = coords + ((size_t)n * M + m) * 3;
    const float cx = cp[0], cy = cp[1], cz = cp[2];

    const uint2* addr[12];
    __half2 wh[12];

    #pragma unroll
    for (int p = 0; p < 3; ++p) {
        const float gxc = (p == 2) ? cz : cx;
        const float gyc = (p == 0) ? cy : ((p == 1) ? cz : cx);
        // exact reference op order: ((g+1)*S - 1) * 0.5
        const float x = ((gxc + 1.0f) * 256.0f - 1.0f) * 0.5f;
        const float y = ((gyc + 1.0f) * 256.0f - 1.0f) * 0.5f;
        const float x0f = floorf(x), y0f = floorf(y);
        const float wx = x - x0f, wy = y - y0f;
        const int x0 = (int)x0f, y0 = (int)y0f;
        const int x1 = x0 + 1,   y1 = y0 + 1;
        const bool vx0 = (unsigned)x0 < 256u;
        const bool vx1 = (unsigned)x1 < 256u;
        const bool vy0 = (unsigned)y0 < 256u;
        const bool vy1 = (unsigned)y1 < 256u;
        const int cx0 = min(max(x0, 0), 255), cx1 = min(max(x1, 0), 255);
        const int cy0 = min(max(y0, 0), 255), cy1 = min(max(y1, 0), 255);

        const float w00 = ((vx0 && vy0) ? 1.f : 0.f) * (1.f - wx) * (1.f - wy);
        const float w10 = ((vx1 && vy0) ? 1.f : 0.f) * wx * (1.f - wy);
        const float w01 = ((vx0 && vy1) ? 1.f : 0.f) * (1.f - wx) * wy;
        const float w11 = ((vx1 && vy1) ? 1.f : 0.f) * wx * wy;
        wh[p * 4 + 0] = __float2half2_rn(w00);
        wh[p * 4 + 1] = __float2half2_rn(w10);
        wh[p * 4 + 2] = __float2half2_rn(w01);
        wh[p * 4 + 3] = __float2half2_rn(w11);

        // pixel record = 32 halves = 8 uint2; lane reads uint2 #quad, #quad+4.
        const uint2* base = reinterpret_cast<const uint2*>(
            tp + (size_t)(n * 3 + p) * HWPIX * Cc);
        addr[p * 4 + 0] = base + (size_t)((cy0 << 8) + cx0) * 8 + quad;
        addr[p * 4 + 1] = base + (size_t)((cy0 << 8) + cx1) * 8 + quad;
        addr[p * 4 + 2] = base + (size_t)((cy1 << 8) + cx0) * 8 + quad;
        addr[p * 4 + 3] = base + (size_t)((cy1 << 8) + cx1) * 8 + quad;
    }

    // Issue all 24 independent 8B loads (low half = channels 4q..4q+3,
    // high half = channels 16+4q..16+4q+3).
    uint2 lo[12], hi[12];
    #pragma unroll
    for (int j = 0; j < 12; ++j) lo[j] = addr[j][0];
    #pragma unroll
    for (int j = 0; j < 12; ++j) hi[j] = addr[j][4];

    float accA[4], accB[4];
    #pragma unroll
    for (int i = 0; i < 4; ++i) { accA[i] = 0.f; accB[i] = 0.f; }

    #pragma unroll
    for (int p = 0; p < 3; ++p) {
        __half2 a0 = __float2half2_rn(0.f), a1 = a0, b0 = a0, b1 = a0;
        #pragma unroll
        for (int c = 0; c < 4; ++c) {
            const int j = p * 4 + c;
            const __half2 w = wh[j];
            a0 = __hfma2(*reinterpret_cast<const __half2*>(&lo[j].x), w, a0);
            a1 = __hfma2(*reinterpret_cast<const __half2*>(&lo[j].y), w, a1);
            b0 = __hfma2(*reinterpret_cast<const __half2*>(&hi[j].x), w, b0);
            b1 = __hfma2(*reinterpret_cast<const __half2*>(&hi[j].y), w, b1);
        }
        const float2 f0 = __half22float2(a0);
        const float2 f1 = __half22float2(a1);
        const float2 g0 = __half22float2(b0);
        const float2 g1 = __half22float2(b1);
        accA[0] += f0.x; accA[1] += f0.y; accA[2] += f1.x; accA[3] += f1.y;
        accB[0] += g0.x; accB[1] += g0.y; accB[2] += g1.x; accB[3] += g1.y;
    }

    constexpr float third = 1.0f / 3.0f;
    float4 oA, oB;
    oA.x = accA[0] * third; oA.y = accA[1] * third;
    oA.z = accA[2] * third; oA.w = accA[3] * third;
    oB.x = accB[0] * third; oB.y = accB[1] * third;
    oB.z = accB[2] * third; oB.w = accB[3] * third;

    // Store float4 #quad (bytes 16q..16q+15) and #quad+4: each instruction
    // covers one contiguous 64B sector across the 4-lane quad.
    float4* op = reinterpret_cast<float4*>(out + ((size_t)n * M + m) * Cc);
    op[quad]     = oA;
    op[quad + 4] = oB;
}

// ---------------------------------------------------------------------------
// Mid tier (ws fits fp16 planes only): unsorted fp16 gather (R3 kernel).
// ---------------------------------------------------------------------------
__global__ __launch_bounds__(256) void triplane_gather_hwc8h(
    const __half* __restrict__ tp, const float* __restrict__ coords,
    float* __restrict__ out, int M)
{
    const int gid   = blockIdx.x * 256 + threadIdx.x;
    const int m     = gid >> 3;
    const int chunk = gid & 7;
    const int n     = blockIdx.y;
    if (m >= M) return;

    const float* cp = coords + ((size_t)n * M + m) * 3;
    const float cx = cp[0], cy = cp[1], cz = cp[2];

    const uint2* addr[12];
    float w[12];

    #pragma unroll
    for (int p = 0; p < 3; ++p) {
        const float gxc = (p == 2) ? cz : cx;
        const float gyc = (p == 0) ? cy : ((p == 1) ? cz : cx);
        const float x = ((gxc + 1.0f) * 256.0f - 1.0f) * 0.5f;
        const float y = ((gyc + 1.0f) * 256.0f - 1.0f) * 0.5f;
        const float x0f = floorf(x), y0f = floorf(y);
        const float wx = x - x0f, wy = y - y0f;
        const int x0 = (int)x0f, y0 = (int)y0f;
        const int x1 = x0 + 1,   y1 = y0 + 1;
        const bool vx0 = (unsigned)x0 < 256u;
        const bool vx1 = (unsigned)x1 < 256u;
        const bool vy0 = (unsigned)y0 < 256u;
        const bool vy1 = (unsigned)y1 < 256u;
        const int cx0 = min(max(x0, 0), 255), cx1 = min(max(x1, 0), 255);
        const int cy0 = min(max(y0, 0), 255), cy1 = min(max(y1, 0), 255);

        w[p * 4 + 0] = ((vx0 && vy0) ? 1.f : 0.f) * (1.f - wx) * (1.f - wy);
        w[p * 4 + 1] = ((vx1 && vy0) ? 1.f : 0.f) * wx * (1.f - wy);
        w[p * 4 + 2] = ((vx0 && vy1) ? 1.f : 0.f) * (1.f - wx) * wy;
        w[p * 4 + 3] = ((vx1 && vy1) ? 1.f : 0.f) * wx * wy;

        const uint2* base = reinterpret_cast<const uint2*>(
            tp + (size_t)(n * 3 + p) * HWPIX * Cc);
        addr[p * 4 + 0] = base + (size_t)((cy0 << 8) + cx0) * 8 + chunk;
        addr[p * 4 + 1] = base + (size_t)((cy0 << 8) + cx1) * 8 + chunk;
        addr[p * 4 + 2] = base + (size_t)((cy1 << 8) + cx0) * 8 + chunk;
        addr[p * 4 + 3] = base + (size_t)((cy1 << 8) + cx1) * 8 + chunk;
    }

    uint2 rv[12];
    #pragma unroll
    for (int j = 0; j < 12; ++j) rv[j] = *addr[j];

    float4 acc = make_float4(0.f, 0.f, 0.f, 0.f);
    #pragma unroll
    for (int j = 0; j < 12; ++j) {
        const __half2 h0 = *reinterpret_cast<const __half2*>(&rv[j].x);
        const __half2 h1 = *reinterpret_cast<const __half2*>(&rv[j].y);
        const float2 f0 = __half22float2(h0);
        const float2 f1 = __half22float2(h1);
        acc.x += w[j] * f0.x;
        acc.y += w[j] * f0.y;
        acc.z += w[j] * f1.x;
        acc.w += w[j] * f1.y;
    }

    constexpr float third = 1.0f / 3.0f;
    acc.x *= third; acc.y *= third; acc.z *= third; acc.w *= third;

    float4* op = reinterpret_cast<float4*>(out + ((size_t)n * M + m) * Cc);
    op[chunk] = acc;
}

// ---------------------------------------------------------------------------
// Fallback (no workspace): gather straight from [C][H][W] f32 layout.
// ---------------------------------------------------------------------------
__global__ __launch_bounds__(256) void triplane_gather_chw(
    const float* __restrict__ planes, const float* __restrict__ coords,
    float* __restrict__ out, int M)
{
    const int m = blockIdx.x * 256 + threadIdx.x;
    const int n = blockIdx.y;
    if (m >= M) return;

    const float* cp = coords + ((size_t)n * M + m) * 3;
    const float cx = cp[0], cy = cp[1], cz = cp[2];

    int   off[3][4];
    float w[3][4];
    #pragma unroll
    for (int p = 0; p < 3; ++p) {
        const float gxc = (p == 2) ? cz : cx;
        const float gyc = (p == 0) ? cy : ((p == 1) ? cz : cx);
        const float x = ((gxc + 1.0f) * 256.0f - 1.0f) * 0.5f;
        const float y = ((gyc + 1.0f) * 256.0f - 1.0f) * 0.5f;
        const float x0f = floorf(x), y0f = floorf(y);
        const float wx = x - x0f, wy = y - y0f;
        const int x0 = (int)x0f, y0 = (int)y0f;
        const int x1 = x0 + 1,   y1 = y0 + 1;
        const bool vx0 = (unsigned)x0 < 256u, vx1 = (unsigned)x1 < 256u;
        const bool vy0 = (unsigned)y0 < 256u, vy1 = (unsigned)y1 < 256u;
        const int cx0 = min(max(x0, 0), 255), cx1 = min(max(x1, 0), 255);
        const int cy0 = min(max(y0, 0), 255), cy1 = min(max(y1, 0), 255);
        off[p][0] = (cy0 << 8) + cx0;  w[p][0] = ((vx0 && vy0) ? 1.f : 0.f) * (1.f - wx) * (1.f - wy);
        off[p][1] = (cy0 << 8) + cx1;  w[p][1] = ((vx1 && vy0) ? 1.f : 0.f) * wx * (1.f - wy);
        off[p][2] = (cy1 << 8) + cx0;  w[p][2] = ((vx0 && vy1) ? 1.f : 0.f) * (1.f - wx) * wy;
        off[p][3] = (cy1 << 8) + cx1;  w[p][3] = ((vx1 && vy1) ? 1.f : 0.f) * wx * wy;
    }

    float* op = out + ((size_t)n * M + m) * Cc;
    constexpr float third = 1.0f / 3.0f;
    for (int c = 0; c < Cc; ++c) {
        float a = 0.f;
        #pragma unroll
        for (int p = 0; p < 3; ++p) {
            const float* b = planes + ((size_t)(n * 3 + p) * Cc + c) * HWPIX;
            a += w[p][0] * b[off[p][0]] + w[p][1] * b[off[p][1]]
               + w[p][2] * b[off[p][2]] + w[p][3] * b[off[p][3]];
        }
        op[c] = a * third;
    }
}

extern "C" void kernel_launch(void* const* d_in, const int* in_sizes, int n_in,
                              void* d_out, int out_size, void* d_ws, size_t ws_size,
                              hipStream_t stream)
{
    const float* planes = (const float*)d_in[0];
    const float* coords = (const float*)d_in[1];
    float* out = (float*)d_out;

    const int M = in_sizes[1] / (Nn * 3);           // 500000

    auto align256 = [](size_t x) { return (x + 255) & ~(size_t)255; };
    const size_t tph_bytes  = align256((size_t)Nn * Pp * HWPIX * Cc * sizeof(__half)); // ~50 MB
    const size_t idx_bytes  = align256((size_t)Nn * NCO * CAP * sizeof(unsigned));     // ~10.5 MB
    const size_t tail_bytes = align256((size_t)Nn * M * sizeof(unsigned));             // ~8 MB
    const size_t cnt_bytes  = align256((size_t)Nn * NCO * sizeof(unsigned));           // 64 KB
    const size_t tc_bytes   = align256((size_t)Nn * sizeof(unsigned));                 // 256 B

    if (ws_size >= tph_bytes + idx_bytes + tail_bytes + cnt_bytes + tc_bytes) {
        char* p = (char*)d_ws;
        __half*   tp      = (__half*)p;   p += tph_bytes;
        unsigned* idx     = (unsigned*)p; p += idx_bytes;
        unsigned* tail    = (unsigned*)p; p += tail_bytes;
        unsigned* count   = (unsigned*)p; p += cnt_bytes;
        unsigned* tailcnt = (unsigned*)p;

        transpose_chw_hwc_h<<<dim3(HWPIX / 256, Nn * Pp), 256, 0, stream>>>(planes, tp);
        zero_u32<<<(Nn * NCO + 255) / 256, 256, 0, stream>>>(count, Nn * NCO);
        zero_u32<<<1, 256, 0, stream>>>(tailcnt, Nn);
        bin_scatter<<<dim3((M + 255) / 256, Nn), 256, 0, stream>>>(
            coords, count, tailcnt, idx, tail, M);

        const int slots = NCO * CAP + M;           // binned + tail slot space
        const int gx    = (slots * 4 + 255) / 256; // 4 lanes per slot
        const int nwg   = Nn * gx;
        triplane_gather_binned<<<nwg, 256, 0, stream>>>(
            tp, count, tailcnt, idx, tail, coords, out, M, slots, gx, nwg);
    } else if (ws_size >= tph_bytes) {
        __half* tp = (__half*)d_ws;
        transpose_chw_hwc_h<<<dim3(HWPIX / 256, Nn * Pp), 256, 0, stream>>>(planes, tp);
        const int gx = (M * 8 + 255) / 256;
        triplane_gather_hwc8h<<<dim3(gx, Nn), 256, 0, stream>>>(tp, coords, out, M);
    } else {
        const int gx = (M + 255) / 256;
        triplane_gather_chw<<<dim3(gx, Nn), 256, 0, stream>>>(planes, coords, out, M);
    }
}

// Round 11
// 284.988 us; speedup vs baseline: 1.4197x; 1.4197x over previous
//
#include <hip/hip_runtime.h>
#include <hip/hip_fp16.h>

// Tri-plane importance-renderer sampling.
// planes: [N=4][P=3][C=32][H=256][W=256] f32
// coords: [N][M=500000][3] f32, directions unused.
// out:    [N][M][C] f32  = mean over P of bilinear samples (zeros padding,
//                          align_corners=False).
// Plane->grid mapping (from inv(_PLANES)): p0:(cx,cy)  p1:(cx,cz)  p2:(cz,cx)
//
// R9 insight: (a) FETCH identical across store patterns -> ~120MB over
// compulsory is L3 plane-eviction by the output stream, not RMW; (b) 8B loads
// + slot holes wasted 2.3x waves (gather 147->252us).
// R10/R11: R8's proven gather body (12x uint4, op[2q]/[2q+1]) + DENSE index
// from one-pass binning + scan + block-per-cell compaction (~40us vs 112us
// counting sort), plus NON-TEMPORAL output stores (via ext_vector alias —
// the HIP_vector_type overload doesn't compile) to keep the 256MB output
// stream out of L3 so planes stay resident.

constexpr int Cc = 32, Hh = 256, Ww = 256, Pp = 3, Nn = 4;
constexpr int HWPIX = Hh * Ww;   // 65536
constexpr int NCO   = 4096;      // 16^3 coarse cells
constexpr int CAP   = 256;       // bin capacity (mean 122; overflow ~0, tail-safe)

typedef float f32x4 __attribute__((ext_vector_type(4)));

__device__ inline unsigned spread3(unsigned x) {
    x &= 0x3FFu;
    x = (x | (x << 16)) & 0x030000FFu;
    x = (x | (x << 8))  & 0x0300F00Fu;
    x = (x | (x << 4))  & 0x030C30C3u;
    x = (x | (x << 2))  & 0x09249249u;
    return x;
}
// 12-bit Morton key from 4 bits/axis.
__device__ inline unsigned coarse_key(float cx, float cy, float cz) {
    const int a = min(max((int)((cx + 1.0f) * 8.0f), 0), 15);
    const int b = min(max((int)((cy + 1.0f) * 8.0f), 0), 15);
    const int c = min(max((int)((cz + 1.0f) * 8.0f), 0), 15);
    return spread3((unsigned)a) | (spread3((unsigned)b) << 1) | (spread3((unsigned)c) << 2);
}

// ---------------------------------------------------------------------------
// Pass 1: transpose+convert [slice][C][HW] f32 -> [slice][HW][C] fp16.
// ---------------------------------------------------------------------------
__global__ __launch_bounds__(256) void transpose_chw_hwc_h(
    const float* __restrict__ in, __half* __restrict__ out)
{
    __shared__ float lds[Cc * 257];
    const int slice = blockIdx.y;
    const int pix0  = blockIdx.x * 256;
    const int t     = threadIdx.x;

    const float* src = in + (size_t)slice * Cc * HWPIX + pix0 + t;
    #pragma unroll
    for (int c = 0; c < Cc; ++c)
        lds[c * 257 + t] = src[(size_t)c * HWPIX];
    __syncthreads();

    uint4* dst = reinterpret_cast<uint4*>(
        out + (size_t)slice * HWPIX * Cc + (size_t)pix0 * Cc);
    #pragma unroll
    for (int k = 0; k < 4; ++k) {
        const int idx = k * 256 + t;
        const int pix = idx >> 2;
        const int c0  = (idx & 3) * 8;
        unsigned r[4];
        #pragma unroll
        for (int j = 0; j < 4; ++j) {
            const __half h0 = __float2half(lds[(c0 + 2 * j + 0) * 257 + pix]);
            const __half h1 = __float2half(lds[(c0 + 2 * j + 1) * 257 + pix]);
            r[j] = (unsigned)__half_as_ushort(h0)
                 | ((unsigned)__half_as_ushort(h1) << 16);
        }
        dst[idx] = make_uint4(r[0], r[1], r[2], r[3]);
    }
}

// ---------------------------------------------------------------------------
// One-pass binning -> scan -> compaction = dense Morton-ordered index.
// ---------------------------------------------------------------------------
__global__ __launch_bounds__(256) void zero_u32(unsigned* __restrict__ p, int n)
{
    const int i = blockIdx.x * 256 + threadIdx.x;
    if (i < n) p[i] = 0u;
}

__global__ __launch_bounds__(256) void bin_scatter(
    const float* __restrict__ coords, unsigned* __restrict__ count,
    unsigned* __restrict__ tailcnt, unsigned* __restrict__ bin,
    unsigned* __restrict__ tail, int M)
{
    const int m = blockIdx.x * 256 + threadIdx.x;
    const int n = blockIdx.y;
    if (m >= M) return;
    const float* cp = coords + ((size_t)n * M + m) * 3;
    const unsigned k = coarse_key(cp[0], cp[1], cp[2]);
    const unsigned r = atomicAdd(&count[n * NCO + k], 1u);
    if (r < CAP) {
        bin[(((size_t)n * NCO + k) << 8) + r] = (unsigned)m;  // 4MB/n window, L2-resident
    } else {
        const unsigned t = atomicAdd(&tailcnt[n], 1u);
        tail[(size_t)n * M + t] = (unsigned)m;
    }
}

// Exclusive scan of min(count,CAP) over 4096 cells; one block per n.
__global__ __launch_bounds__(1024) void cell_scan_base(
    const unsigned* __restrict__ count, unsigned* __restrict__ base)
{
    __shared__ unsigned lds[1024];
    const unsigned* h = count + (size_t)blockIdx.x * NCO;
    unsigned* o = base + (size_t)blockIdx.x * NCO;
    const int t = threadIdx.x;
    unsigned v[4];
    unsigned s = 0;
    #pragma unroll
    for (int i = 0; i < 4; ++i) { v[i] = min(h[t * 4 + i], (unsigned)CAP); s += v[i]; }
    lds[t] = s;
    __syncthreads();
    for (int d = 1; d < 1024; d <<= 1) {
        const unsigned add = (t >= d) ? lds[t - d] : 0u;
        __syncthreads();
        lds[t] += add;
        __syncthreads();
    }
    unsigned b = (t > 0) ? lds[t - 1] : 0u;
    #pragma unroll
    for (int i = 0; i < 4; ++i) { const unsigned tmp = v[i]; o[t * 4 + i] = b; b += tmp; }
}

// Block = cell: copy min(count,CAP) bin entries to dense[base..], coalesced.
__global__ __launch_bounds__(256) void compact_cells(
    const unsigned* __restrict__ count, const unsigned* __restrict__ base,
    const unsigned* __restrict__ bin, unsigned* __restrict__ dense, int M)
{
    const int n = blockIdx.y, cell = blockIdx.x, t = threadIdx.x;
    const unsigned c = min(count[n * NCO + cell], (unsigned)CAP);
    if ((unsigned)t < c)
        dense[(size_t)n * M + base[n * NCO + cell] + t] =
            bin[(((size_t)n * NCO + cell) << 8) + t];
}

// Append tail entries (usually zero) at dense[M - tailcnt ..].
__global__ __launch_bounds__(256) void tail_copy(
    const unsigned* __restrict__ tailcnt, const unsigned* __restrict__ tail,
    unsigned* __restrict__ dense, int M)
{
    const int n = blockIdx.x;
    const unsigned tc = tailcnt[n];
    for (unsigned t = threadIdx.x; t < tc; t += 256)
        dense[(size_t)n * M + (M - tc) + t] = tail[(size_t)n * M + t];
}

// ---------------------------------------------------------------------------
// Gather in Morton order (R8's proven body). FOUR lanes per sample, 8 fp16
// channels each (one uint4 per corner). Per-plane packed __hfma2, cross-plane
// f32. Non-temporal output stores (keep the 256MB stream out of L3 so planes
// stay resident). Bijective XCD-chunked swizzle.
// ---------------------------------------------------------------------------
__global__ __launch_bounds__(256) void triplane_gather4h(
    const __half* __restrict__ tp, const unsigned* __restrict__ idx,
    const float* __restrict__ coords, float* __restrict__ out,
    int M, int gx, int nwg)
{
    int bid = blockIdx.x;
    {   // bijective chunked XCD swizzle (m204 form)
        const int q = nwg >> 3, r = nwg & 7;
        const int xcd = bid & 7, i = bid >> 3;
        bid = (xcd < r ? xcd * (q + 1) : r * (q + 1) + (xcd - r) * q) + i;
    }
    const int n  = bid / gx;
    const int bx = bid - n * gx;
    const int gid  = bx * 256 + threadIdx.x;
    const int s    = gid >> 2;
    const int quad = gid & 3;            // 8-channel group
    if (s >= M) return;

    const int m = (int)idx[(size_t)n * M + s];
    const float* cp = coords + ((size_t)n * M + m) * 3;
    const float cx = cp[0], cy = cp[1], cz = cp[2];

    const uint4* addr[12];
    __half2 wh[12];

    #pragma unroll
    for (int p = 0; p < 3; ++p) {
        const float gxc = (p == 2) ? cz : cx;
        const float gyc = (p == 0) ? cy : ((p == 1) ? cz : cx);
        // exact reference op order: ((g+1)*S - 1) * 0.5
        const float x = ((gxc + 1.0f) * 256.0f - 1.0f) * 0.5f;
        const float y = ((gyc + 1.0f) * 256.0f - 1.0f) * 0.5f;
        const float x0f = floorf(x), y0f = floorf(y);
        const float wx = x - x0f, wy = y - y0f;
        const int x0 = (int)x0f, y0 = (int)y0f;
        const int x1 = x0 + 1,   y1 = y0 + 1;
        const bool vx0 = (unsigned)x0 < 256u;
        const bool vx1 = (unsigned)x1 < 256u;
        const bool vy0 = (unsigned)y0 < 256u;
        const bool vy1 = (unsigned)y1 < 256u;
        const int cx0 = min(max(x0, 0), 255), cx1 = min(max(x1, 0), 255);
        const int cy0 = min(max(y0, 0), 255), cy1 = min(max(y1, 0), 255);

        const float w00 = ((vx0 && vy0) ? 1.f : 0.f) * (1.f - wx) * (1.f - wy);
        const float w10 = ((vx1 && vy0) ? 1.f : 0.f) * wx * (1.f - wy);
        const float w01 = ((vx0 && vy1) ? 1.f : 0.f) * (1.f - wx) * wy;
        const float w11 = ((vx1 && vy1) ? 1.f : 0.f) * wx * wy;
        wh[p * 4 + 0] = __float2half2_rn(w00);
        wh[p * 4 + 1] = __float2half2_rn(w10);
        wh[p * 4 + 2] = __float2half2_rn(w01);
        wh[p * 4 + 3] = __float2half2_rn(w11);

        // pixel record = 32 halves = 4 uint4; lane reads uint4 #quad.
        const uint4* base = reinterpret_cast<const uint4*>(
            tp + (size_t)(n * 3 + p) * HWPIX * Cc);
        addr[p * 4 + 0] = base + (size_t)((cy0 << 8) + cx0) * 4 + quad;
        addr[p * 4 + 1] = base + (size_t)((cy0 << 8) + cx1) * 4 + quad;
        addr[p * 4 + 2] = base + (size_t)((cy1 << 8) + cx0) * 4 + quad;
        addr[p * 4 + 3] = base + (size_t)((cy1 << 8) + cx1) * 4 + quad;
    }

    // Issue all 12 independent 16B loads.
    uint4 rv[12];
    #pragma unroll
    for (int j = 0; j < 12; ++j) rv[j] = *addr[j];

    float accx[8];
    #pragma unroll
    for (int i = 0; i < 8; ++i) accx[i] = 0.f;

    #pragma unroll
    for (int p = 0; p < 3; ++p) {
        __half2 a0 = __float2half2_rn(0.f), a1 = a0, a2 = a0, a3 = a0;
        #pragma unroll
        for (int c = 0; c < 4; ++c) {
            const uint4 v = rv[p * 4 + c];
            const __half2 w = wh[p * 4 + c];
            a0 = __hfma2(*reinterpret_cast<const __half2*>(&v.x), w, a0);
            a1 = __hfma2(*reinterpret_cast<const __half2*>(&v.y), w, a1);
            a2 = __hfma2(*reinterpret_cast<const __half2*>(&v.z), w, a2);
            a3 = __hfma2(*reinterpret_cast<const __half2*>(&v.w), w, a3);
        }
        const float2 f0 = __half22float2(a0);
        const float2 f1 = __half22float2(a1);
        const float2 f2 = __half22float2(a2);
        const float2 f3 = __half22float2(a3);
        accx[0] += f0.x; accx[1] += f0.y;
        accx[2] += f1.x; accx[3] += f1.y;
        accx[4] += f2.x; accx[5] += f2.y;
        accx[6] += f3.x; accx[7] += f3.y;
    }

    constexpr float third = 1.0f / 3.0f;
    f32x4 o0, o1;
    o0.x = accx[0] * third; o0.y = accx[1] * third;
    o0.z = accx[2] * third; o0.w = accx[3] * third;
    o1.x = accx[4] * third; o1.y = accx[5] * third;
    o1.z = accx[6] * third; o1.w = accx[7] * third;

    // Non-temporal 16B stores via ext_vector pointer (native clang vector).
    f32x4* op = reinterpret_cast<f32x4*>(out + ((size_t)n * M + m) * Cc);
    __builtin_nontemporal_store(o0, op + quad * 2 + 0);
    __builtin_nontemporal_store(o1, op + quad * 2 + 1);
}

// ---------------------------------------------------------------------------
// Mid tier (ws fits fp16 planes only): unsorted fp16 gather (R3 kernel).
// ---------------------------------------------------------------------------
__global__ __launch_bounds__(256) void triplane_gather_hwc8h(
    const __half* __restrict__ tp, const float* __restrict__ coords,
    float* __restrict__ out, int M)
{
    const int gid   = blockIdx.x * 256 + threadIdx.x;
    const int m     = gid >> 3;
    const int chunk = gid & 7;
    const int n     = blockIdx.y;
    if (m >= M) return;

    const float* cp = coords + ((size_t)n * M + m) * 3;
    const float cx = cp[0], cy = cp[1], cz = cp[2];

    const uint2* addr[12];
    float w[12];

    #pragma unroll
    for (int p = 0; p < 3; ++p) {
        const float gxc = (p == 2) ? cz : cx;
        const float gyc = (p == 0) ? cy : ((p == 1) ? cz : cx);
        const float x = ((gxc + 1.0f) * 256.0f - 1.0f) * 0.5f;
        const float y = ((gyc + 1.0f) * 256.0f - 1.0f) * 0.5f;
        const float x0f = floorf(x), y0f = floorf(y);
        const float wx = x - x0f, wy = y - y0f;
        const int x0 = (int)x0f, y0 = (int)y0f;
        const int x1 = x0 + 1,   y1 = y0 + 1;
        const bool vx0 = (unsigned)x0 < 256u;
        const bool vx1 = (unsigned)x1 < 256u;
        const bool vy0 = (unsigned)y0 < 256u;
        const bool vy1 = (unsigned)y1 < 256u;
        const int cx0 = min(max(x0, 0), 255), cx1 = min(max(x1, 0), 255);
        const int cy0 = min(max(y0, 0), 255), cy1 = min(max(y1, 0), 255);

        w[p * 4 + 0] = ((vx0 && vy0) ? 1.f : 0.f) * (1.f - wx) * (1.f - wy);
        w[p * 4 + 1] = ((vx1 && vy0) ? 1.f : 0.f) * wx * (1.f - wy);
        w[p * 4 + 2] = ((vx0 && vy1) ? 1.f : 0.f) * (1.f - wx) * wy;
        w[p * 4 + 3] = ((vx1 && vy1) ? 1.f : 0.f) * wx * wy;

        const uint2* base = reinterpret_cast<const uint2*>(
            tp + (size_t)(n * 3 + p) * HWPIX * Cc);
        addr[p * 4 + 0] = base + (size_t)((cy0 << 8) + cx0) * 8 + chunk;
        addr[p * 4 + 1] = base + (size_t)((cy0 << 8) + cx1) * 8 + chunk;
        addr[p * 4 + 2] = base + (size_t)((cy1 << 8) + cx0) * 8 + chunk;
        addr[p * 4 + 3] = base + (size_t)((cy1 << 8) + cx1) * 8 + chunk;
    }

    uint2 rv[12];
    #pragma unroll
    for (int j = 0; j < 12; ++j) rv[j] = *addr[j];

    float4 acc = make_float4(0.f, 0.f, 0.f, 0.f);
    #pragma unroll
    for (int j = 0; j < 12; ++j) {
        const __half2 h0 = *reinterpret_cast<const __half2*>(&rv[j].x);
        const __half2 h1 = *reinterpret_cast<const __half2*>(&rv[j].y);
        const float2 f0 = __half22float2(h0);
        const float2 f1 = __half22float2(h1);
        acc.x += w[j] * f0.x;
        acc.y += w[j] * f0.y;
        acc.z += w[j] * f1.x;
        acc.w += w[j] * f1.y;
    }

    constexpr float third = 1.0f / 3.0f;
    acc.x *= third; acc.y *= third; acc.z *= third; acc.w *= third;

    float4* op = reinterpret_cast<float4*>(out + ((size_t)n * M + m) * Cc);
    op[chunk] = acc;
}

// ---------------------------------------------------------------------------
// Fallback (no workspace): gather straight from [C][H][W] f32 layout.
// ---------------------------------------------------------------------------
__global__ __launch_bounds__(256) void triplane_gather_chw(
    const float* __restrict__ planes, const float* __restrict__ coords,
    float* __restrict__ out, int M)
{
    const int m = blockIdx.x * 256 + threadIdx.x;
    const int n = blockIdx.y;
    if (m >= M) return;

    const float* cp = coords + ((size_t)n * M + m) * 3;
    const float cx = cp[0], cy = cp[1], cz = cp[2];

    int   off[3][4];
    float w[3][4];
    #pragma unroll
    for (int p = 0; p < 3; ++p) {
        const float gxc = (p == 2) ? cz : cx;
        const float gyc = (p == 0) ? cy : ((p == 1) ? cz : cx);
        const float x = ((gxc + 1.0f) * 256.0f - 1.0f) * 0.5f;
        const float y = ((gyc + 1.0f) * 256.0f - 1.0f) * 0.5f;
        const float x0f = floorf(x), y0f = floorf(y);
        const float wx = x - x0f, wy = y - y0f;
        const int x0 = (int)x0f, y0 = (int)y0f;
        const int x1 = x0 + 1,   y1 = y0 + 1;
        const bool vx0 = (unsigned)x0 < 256u, vx1 = (unsigned)x1 < 256u;
        const bool vy0 = (unsigned)y0 < 256u, vy1 = (unsigned)y1 < 256u;
        const int cx0 = min(max(x0, 0), 255), cx1 = min(max(x1, 0), 255);
        const int cy0 = min(max(y0, 0), 255), cy1 = min(max(y1, 0), 255);
        off[p][0] = (cy0 << 8) + cx0;  w[p][0] = ((vx0 && vy0) ? 1.f : 0.f) * (1.f - wx) * (1.f - wy);
        off[p][1] = (cy0 << 8) + cx1;  w[p][1] = ((vx1 && vy0) ? 1.f : 0.f) * wx * (1.f - wy);
        off[p][2] = (cy1 << 8) + cx0;  w[p][2] = ((vx0 && vy1) ? 1.f : 0.f) * (1.f - wx) * wy;
        off[p][3] = (cy1 << 8) + cx1;  w[p][3] = ((vx1 && vy1) ? 1.f : 0.f) * wx * wy;
    }

    float* op = out + ((size_t)n * M + m) * Cc;
    constexpr float third = 1.0f / 3.0f;
    for (int c = 0; c < Cc; ++c) {
        float a = 0.f;
        #pragma unroll
        for (int p = 0; p < 3; ++p) {
            const float* b = planes + ((size_t)(n * 3 + p) * Cc + c) * HWPIX;
            a += w[p][0] * b[off[p][0]] + w[p][1] * b[off[p][1]]
               + w[p][2] * b[off[p][2]] + w[p][3] * b[off[p][3]];
        }
        op[c] = a * third;
    }
}

extern "C" void kernel_launch(void* const* d_in, const int* in_sizes, int n_in,
                              void* d_out, int out_size, void* d_ws, size_t ws_size,
                              hipStream_t stream)
{
    const float* planes = (const float*)d_in[0];
    const float* coords = (const float*)d_in[1];
    float* out = (float*)d_out;

    const int M = in_sizes[1] / (Nn * 3);           // 500000

    auto align256 = [](size_t x) { return (x + 255) & ~(size_t)255; };
    const size_t tph_bytes   = align256((size_t)Nn * Pp * HWPIX * Cc * sizeof(__half)); // ~50 MB
    const size_t bin_bytes   = align256((size_t)Nn * NCO * CAP * sizeof(unsigned));     // ~16.8 MB
    const size_t dense_bytes = align256((size_t)Nn * M * sizeof(unsigned));             // ~8 MB
    const size_t tail_bytes  = align256((size_t)Nn * M * sizeof(unsigned));             // ~8 MB
    const size_t cnt_bytes   = align256((size_t)Nn * NCO * sizeof(unsigned));           // 64 KB
    const size_t base_bytes  = align256((size_t)Nn * NCO * sizeof(unsigned));           // 64 KB
    const size_t tc_bytes    = align256((size_t)Nn * sizeof(unsigned));                 // 256 B

    const size_t need = tph_bytes + bin_bytes + dense_bytes + tail_bytes +
                        cnt_bytes + base_bytes + tc_bytes;

    if (ws_size >= need) {
        char* p = (char*)d_ws;
        __half*   tp      = (__half*)p;   p += tph_bytes;
        unsigned* bin     = (unsigned*)p; p += bin_bytes;
        unsigned* dense   = (unsigned*)p; p += dense_bytes;
        unsigned* tail    = (unsigned*)p; p += tail_bytes;
        unsigned* count   = (unsigned*)p; p += cnt_bytes;
        unsigned* base    = (unsigned*)p; p += base_bytes;
        unsigned* tailcnt = (unsigned*)p;

        transpose_chw_hwc_h<<<dim3(HWPIX / 256, Nn * Pp), 256, 0, stream>>>(planes, tp);
        zero_u32<<<(Nn * NCO + 255) / 256, 256, 0, stream>>>(count, Nn * NCO);
        zero_u32<<<1, 256, 0, stream>>>(tailcnt, Nn);
        bin_scatter<<<dim3((M + 255) / 256, Nn), 256, 0, stream>>>(
            coords, count, tailcnt, bin, tail, M);
        cell_scan_base<<<Nn, 1024, 0, stream>>>(count, base);
        compact_cells<<<dim3(NCO, Nn), 256, 0, stream>>>(count, base, bin, dense, M);
        tail_copy<<<Nn, 256, 0, stream>>>(tailcnt, tail, dense, M);

        const int gx  = (M * 4 + 255) / 256;   // 4 lanes per sample
        const int nwg = Nn * gx;
        triplane_gather4h<<<nwg, 256, 0, stream>>>(tp, dense, coords, out, M, gx, nwg);
    } else if (ws_size >= tph_bytes) {
        __half* tp = (__half*)d_ws;
        transpose_chw_hwc_h<<<dim3(HWPIX / 256, Nn * Pp), 256, 0, stream>>>(planes, tp);
        const int gx = (M * 8 + 255) / 256;
        triplane_gather_hwc8h<<<dim3(gx, Nn), 256, 0, stream>>>(tp, coords, out, M);
    } else {
        const int gx = (M + 255) / 256;
        triplane_gather_chw<<<dim3(gx, Nn), 256, 0, stream>>>(planes, coords, out, M);
    }
}